// Round 3
// baseline (115.167 us; speedup 1.0000x reference)
//
#include <hip/hip_runtime.h>
#include <hip/hip_bf16.h>

// ScoreNet fused: central moments -> MLP -> analytic jacobian contraction.
// out[b,n,:] = per-point cubic polynomial in centered coords (u,v) with
// coefficients from h, minus a per-sample mean-shift constant whose monomial
// sums are zero (degree-1, centered) or equal lower-order moments.
// All tensors fp32 (verified round 2: passed with absmax 4.0).

// Fast exact-enough GELU: Abramowitz-Stegun 7.1.26 erf (max err 1.5e-7),
// branch-free, v_rcp_f32 + v_exp_f32. Replaces libm erff (~30 instr w/
// branches) with ~14 instr.
static __device__ __forceinline__ float gelu_f(float x) {
    float y = 0.7071067811865475f * x;
    float s = fabsf(y);
    float t = __builtin_amdgcn_rcpf(fmaf(0.3275911f, s, 1.0f));
    float p = t * fmaf(t, fmaf(t, fmaf(t, fmaf(t, 1.061405429f,
                    -1.453152027f), 1.421413741f), -0.284496736f), 0.254829592f);
    float e = __expf(-y * y);          // underflows to 0 for |y|>~9.3 -> erf=+-1 exactly
    float ea = fmaf(-p, e, 1.0f);      // erf(|y|)
    float erfv = copysignf(ea, y);
    return 0.5f * x * (1.0f + erfv);
}

#define TWO_PI_F 6.283185307179586f

__global__ __launch_bounds__(256) void scorenet_fused(
    const float* __restrict__ x,      // [B,100,2]
    const float* __restrict__ t_in,   // [1]
    const float* __restrict__ Wf,     // [32]
    const float* __restrict__ embW,   // [64,64]
    const float* __restrict__ embB,   // [64]
    const float* __restrict__ W1,     // [12,64]
    const float* __restrict__ b1,     // [64]
    const float* __restrict__ W2a,    // [64,128]
    const float* __restrict__ b2a,    // [128]
    const float* __restrict__ W2b,    // [128,12]
    const float* __restrict__ b2b,    // [12]
    const float* __restrict__ W2c,    // [12,12]
    const float* __restrict__ b2c,    // [12]
    float* __restrict__ out,          // [B,100,2]
    int B)
{
    __shared__ float s_f[64];
    __shared__ float s_emb[64];
    __shared__ float s_aval[4][64];   // per-wave h1+emb broadcast buffer

    const int tid = threadIdx.x;
    const float tval = t_in[0];

    // Phase 0: Gaussian-Fourier time embedding (sample-independent), once per block.
    if (tid < 32) {
        float xp = tval * Wf[tid] * TWO_PI_F;
        s_f[tid]      = sinf(xp);
        s_f[tid + 32] = cosf(xp);
    }
    __syncthreads();
    if (tid < 64) {
        float acc = embB[tid];
        #pragma unroll 8
        for (int j = 0; j < 64; ++j) acc += s_f[j] * embW[j * 64 + tid];
        s_emb[tid] = acc;
    }
    __syncthreads();

    const int lane = tid & 63;
    const int wv = tid >> 6;
    const int b = blockIdx.x * 4 + wv;
    if (b >= B) return;

    // ---- load this sample's points: lane -> point lane, and lane+64 (if <100)
    const float2* px = reinterpret_cast<const float2*>(x) + (size_t)b * 100;
    const bool has2 = lane < 36;

    float2 p0 = px[lane];
    float2 p1 = px[has2 ? lane + 64 : lane];
    float xa = p0.x, ya = p0.y;
    float xb = has2 ? p1.x : 0.0f;
    float yb = has2 ? p1.y : 0.0f;

    // ---- mean over 100 points (wave butterfly)
    float sx = xa + xb, sy = ya + yb;
    #pragma unroll
    for (int off = 32; off; off >>= 1) {
        sx += __shfl_xor(sx, off);
        sy += __shfl_xor(sy, off);
    }
    const float mux = sx * 0.01f, muy = sy * 0.01f;

    float ua = xa - mux, va = ya - muy;
    float ub = has2 ? (xb - mux) : 0.0f;   // zero => contributes 0 to all monomials
    float vb = has2 ? (yb - muy) : 0.0f;

    // ---- 12 central-moment monomial sums
    // order: (1,1)(2,0)(0,2)(2,1)(1,2)(3,0)(0,3)(2,2)(3,1)(1,3)(4,0)(0,4)
    float ms[12];
    {
        float u2 = ua * ua, v2 = va * va;
        ms[0] = ua * va;   ms[1] = u2;        ms[2] = v2;
        ms[3] = u2 * va;   ms[4] = ua * v2;
        ms[5] = u2 * ua;   ms[6] = v2 * va;
        ms[7] = u2 * v2;   ms[8] = ms[5] * va; ms[9] = ua * ms[6];
        ms[10] = u2 * u2;  ms[11] = v2 * v2;
        float w2 = ub * ub, z2 = vb * vb;
        ms[0] += ub * vb;  ms[1] += w2;       ms[2] += z2;
        ms[3] += w2 * vb;  ms[4] += ub * z2;
        ms[5] += w2 * ub;  ms[6] += z2 * vb;
        ms[7] += w2 * z2;  ms[8] += w2 * ub * vb; ms[9] += ub * z2 * vb;
        ms[10] += w2 * w2; ms[11] += z2 * z2;
    }
    float m[12];
    #pragma unroll
    for (int k = 0; k < 12; ++k) {
        float s = ms[k];
        #pragma unroll
        for (int off = 32; off; off >>= 1) s += __shfl_xor(s, off);
        m[k] = s;
    }

    // ---- MLP: h1 = gelu(m @ W1 + b1); lane owns unit `lane`
    float a1 = b1[lane];
    #pragma unroll
    for (int k = 0; k < 12; ++k) a1 += m[k] * W1[k * 64 + lane];
    float aval = gelu_f(a1) + s_emb[lane];

    // ---- h2 = gelu((h1+emb) @ W2a + b2a); lane owns units lane, lane+64.
    // Broadcast aval through per-wave LDS (b128 broadcast reads, conflict-free)
    // instead of a 64-deep __shfl chain.
    s_aval[wv][lane] = aval;
    const float4* av = reinterpret_cast<const float4*>(&s_aval[wv][0]);
    float acc0 = b2a[lane];
    float acc1 = b2a[lane + 64];
    #pragma unroll
    for (int c = 0; c < 16; ++c) {
        float4 a4 = av[c];
        int j = 4 * c;
        acc0 = fmaf(a4.x, W2a[(j+0)*128 + lane],
               fmaf(a4.y, W2a[(j+1)*128 + lane],
               fmaf(a4.z, W2a[(j+2)*128 + lane],
               fmaf(a4.w, W2a[(j+3)*128 + lane], acc0))));
        acc1 = fmaf(a4.x, W2a[(j+0)*128 + 64 + lane],
               fmaf(a4.y, W2a[(j+1)*128 + 64 + lane],
               fmaf(a4.z, W2a[(j+2)*128 + 64 + lane],
               fmaf(a4.w, W2a[(j+3)*128 + 64 + lane], acc1))));
    }
    float h2lo = gelu_f(acc0), h2hi = gelu_f(acc1);

    // ---- h3 = gelu(h2 @ W2b + b2b): per-lane partials + 12-value butterfly
    float h3[12];
    {
        float p3[12];
        #pragma unroll
        for (int k = 0; k < 12; ++k)
            p3[k] = fmaf(h2lo, W2b[lane * 12 + k], h2hi * W2b[(lane + 64) * 12 + k]);
        #pragma unroll
        for (int k = 0; k < 12; ++k) {
            float s = p3[k];
            #pragma unroll
            for (int off = 32; off; off >>= 1) s += __shfl_xor(s, off);
            h3[k] = gelu_f(s + b2b[k]);
        }
    }

    // ---- h = (h3 @ W2c + b2c) / sqrt(t)   (computed redundantly on all lanes;
    // W2c/b2c are wave-uniform -> scalar loads, FMA with SGPR operand)
    const float rst = rsqrtf(tval);
    float h[12];
    #pragma unroll
    for (int k = 0; k < 12; ++k) {
        float acc = b2c[k];
        #pragma unroll
        for (int j = 0; j < 12; ++j) acc = fmaf(h3[j], W2c[j * 12 + k], acc);
        h[k] = acc * rst;
    }

    // ---- per-sample correction constants (mean-shift term of the jacobian).
    // S0_k = sum u^(P-1) v^Q: degree-1 sums vanish (centered); others are moments.
    const float inv_n = 0.01f;
    float c0 = (2.0f*h[3]*m[0] + h[4]*m[2] + 3.0f*h[5]*m[1] + 2.0f*h[7]*m[4]
              + 3.0f*h[8]*m[3] + h[9]*m[6] + 4.0f*h[10]*m[5]) * inv_n;
    float c1 = (h[3]*m[1] + 2.0f*h[4]*m[0] + 3.0f*h[6]*m[2] + 2.0f*h[7]*m[3]
              + h[8]*m[5] + 3.0f*h[9]*m[4] + 4.0f*h[11]*m[6]) * inv_n;

    // cubic polynomial coefficients in (u, v)
    const float A1 = 2.0f*h[1], A2 = h[0],      A3 = 3.0f*h[5], A4 = 2.0f*h[3], A5 = h[4];
    const float A6 = 4.0f*h[10],A7 = 3.0f*h[8], A8 = 2.0f*h[7], A9 = h[9];
    const float B1 = h[0],      B2 = 2.0f*h[2], B3 = h[3],      B4 = 2.0f*h[4], B5 = 3.0f*h[6];
    const float B6 = h[8],      B7 = 2.0f*h[7], B8 = 3.0f*h[9], B9 = 4.0f*h[11];

    float2* pout = reinterpret_cast<float2*>(out) + (size_t)b * 100;
    {
        float u = ua, v = va;
        float u2 = u*u, v2 = v*v;
        float o0 = A1*u + A2*v + A3*u2 + A4*u*v + A5*v2 + A6*u2*u + A7*u2*v + A8*u*v2 + A9*v2*v - c0;
        float o1 = B1*u + B2*v + B3*u2 + B4*u*v + B5*v2 + B6*u2*u + B7*u2*v + B8*u*v2 + B9*v2*v - c1;
        float2 r; r.x = o0; r.y = o1;
        pout[lane] = r;
    }
    if (has2) {
        float u = ub, v = vb;
        float u2 = u*u, v2 = v*v;
        float o0 = A1*u + A2*v + A3*u2 + A4*u*v + A5*v2 + A6*u2*u + A7*u2*v + A8*u*v2 + A9*v2*v - c0;
        float o1 = B1*u + B2*v + B3*u2 + B4*u*v + B5*v2 + B6*u2*u + B7*u2*v + B8*u*v2 + B9*v2*v - c1;
        float2 r; r.x = o0; r.y = o1;
        pout[lane + 64] = r;
    }
}

extern "C" void kernel_launch(void* const* d_in, const int* in_sizes, int n_in,
                              void* d_out, int out_size, void* d_ws, size_t ws_size,
                              hipStream_t stream) {
    const float* x    = (const float*)d_in[0];
    const float* t    = (const float*)d_in[1];
    // d_in[2] = K (exponent table) — baked into the kernel as compile-time constants.
    const float* Wf   = (const float*)d_in[3];
    const float* embW = (const float*)d_in[4];
    const float* embB = (const float*)d_in[5];
    const float* W1   = (const float*)d_in[6];
    const float* b1   = (const float*)d_in[7];
    const float* W2a  = (const float*)d_in[8];
    const float* b2a  = (const float*)d_in[9];
    const float* W2b  = (const float*)d_in[10];
    const float* b2b  = (const float*)d_in[11];
    const float* W2c  = (const float*)d_in[12];
    const float* b2c  = (const float*)d_in[13];

    const int B = in_sizes[0] / 200;            // [B,100,2]
    const int blocks = (B + 3) / 4;             // 4 samples (waves) per block

    scorenet_fused<<<blocks, 256, 0, stream>>>(
        x, t, Wf, embW, embB, W1, b1, W2a, b2a, W2b, b2b, W2c, b2c,
        (float*)d_out, B);
}

// Round 4
// 103.185 us; speedup vs baseline: 1.1161x; 1.1161x over previous
//
#include <hip/hip_runtime.h>
#include <hip/hip_bf16.h>

// ScoreNet fused: central moments -> MLP -> analytic jacobian contraction.
// Round 4: all cross-lane reductions moved from the DS pipe (__shfl_xor =
// ds_swizzle, ~120 cyc chained latency, shared DS unit) to VALU DPP adds
// (row_shr + row_bcast, ~2 cyc each). r3 counters: VALUBusy 24%, HBM 2.7%,
// 0 bank conflicts -> latency-bound on DS chains, VALU mostly idle.

static __device__ __forceinline__ float gelu_f(float x) {
    // Abramowitz-Stegun 7.1.26 erf (max err 1.5e-7), branch-free.
    float y = 0.7071067811865475f * x;
    float s = fabsf(y);
    float t = __builtin_amdgcn_rcpf(fmaf(0.3275911f, s, 1.0f));
    float p = t * fmaf(t, fmaf(t, fmaf(t, fmaf(t, 1.061405429f,
                    -1.453152027f), 1.421413741f), -0.284496736f), 0.254829592f);
    float e = __expf(-y * y);
    float ea = fmaf(-p, e, 1.0f);
    float erfv = copysignf(ea, y);
    return 0.5f * x * (1.0f + erfv);
}

// Wave64 sum via DPP: row_shr 1/2/4/8 accumulates lane 15 (mod 16) = row sum,
// row_bcast:15 folds rows 0->1, 2->3; row_bcast:31 folds halves; lane 63 has
// the total. bound_ctrl=true: invalid-source lanes read 0 (harmless for +).
// Result broadcast to all lanes via readlane (SGPR, wave-uniform).
#define DPP_ADD(v, ctrl) \
    v += __int_as_float(__builtin_amdgcn_update_dpp(0, __float_as_int(v), ctrl, 0xf, 0xf, true))

static __device__ __forceinline__ float wave_sum(float v) {
    DPP_ADD(v, 0x111);  // row_shr:1
    DPP_ADD(v, 0x112);  // row_shr:2
    DPP_ADD(v, 0x114);  // row_shr:4
    DPP_ADD(v, 0x118);  // row_shr:8
    DPP_ADD(v, 0x142);  // row_bcast:15
    DPP_ADD(v, 0x143);  // row_bcast:31
    return __int_as_float(__builtin_amdgcn_readlane(__float_as_int(v), 63));
}

#define TWO_PI_F 6.283185307179586f

__global__ __launch_bounds__(256) void scorenet_fused(
    const float* __restrict__ x,      // [B,100,2]
    const float* __restrict__ t_in,   // [1]
    const float* __restrict__ Wf,     // [32]
    const float* __restrict__ embW,   // [64,64]
    const float* __restrict__ embB,   // [64]
    const float* __restrict__ W1,     // [12,64]
    const float* __restrict__ b1,     // [64]
    const float* __restrict__ W2a,    // [64,128]
    const float* __restrict__ b2a,    // [128]
    const float* __restrict__ W2b,    // [128,12]
    const float* __restrict__ b2b,    // [12]
    const float* __restrict__ W2c,    // [12,12]
    const float* __restrict__ b2c,    // [12]
    float* __restrict__ out,          // [B,100,2]
    int B)
{
    __shared__ float s_f[64];
    __shared__ float s_emb[64];

    const int tid = threadIdx.x;
    const float tval = t_in[0];

    // Phase 0: Gaussian-Fourier time embedding (sample-independent), once per block.
    if (tid < 32) {
        float xp = tval * Wf[tid] * TWO_PI_F;
        s_f[tid]      = sinf(xp);
        s_f[tid + 32] = cosf(xp);
    }
    __syncthreads();
    if (tid < 64) {
        float acc = embB[tid];
        const float4* f4 = reinterpret_cast<const float4*>(s_f);
        #pragma unroll
        for (int c = 0; c < 16; ++c) {
            float4 a4 = f4[c];     // broadcast LDS read, conflict-free
            int j = 4 * c;
            acc = fmaf(a4.x, embW[(j+0)*64 + tid],
                  fmaf(a4.y, embW[(j+1)*64 + tid],
                  fmaf(a4.z, embW[(j+2)*64 + tid],
                  fmaf(a4.w, embW[(j+3)*64 + tid], acc))));
        }
        s_emb[tid] = acc;
    }
    __syncthreads();

    const int lane = tid & 63;
    const int b = blockIdx.x * 4 + (tid >> 6);
    if (b >= B) return;

    // ---- load this sample's points: lane -> point lane, and lane+64 (if <100)
    const float2* px = reinterpret_cast<const float2*>(x) + (size_t)b * 100;
    const bool has2 = lane < 36;

    float2 p0 = px[lane];
    float2 p1 = px[has2 ? lane + 64 : lane];
    float xa = p0.x, ya = p0.y;
    float xb = has2 ? p1.x : 0.0f;
    float yb = has2 ? p1.y : 0.0f;

    // ---- mean over 100 points (DPP wave sums -> uniform scalars)
    const float mux = wave_sum(xa + xb) * 0.01f;
    const float muy = wave_sum(ya + yb) * 0.01f;

    float ua = xa - mux, va = ya - muy;
    float ub = has2 ? (xb - mux) : 0.0f;   // zero => contributes 0 to all monomials
    float vb = has2 ? (yb - muy) : 0.0f;

    // ---- 12 central-moment monomial sums
    // order: (1,1)(2,0)(0,2)(2,1)(1,2)(3,0)(0,3)(2,2)(3,1)(1,3)(4,0)(0,4)
    float ms[12];
    {
        float u2 = ua * ua, v2 = va * va;
        ms[0] = ua * va;   ms[1] = u2;        ms[2] = v2;
        ms[3] = u2 * va;   ms[4] = ua * v2;
        ms[5] = u2 * ua;   ms[6] = v2 * va;
        ms[7] = u2 * v2;   ms[8] = ms[5] * va; ms[9] = ua * ms[6];
        ms[10] = u2 * u2;  ms[11] = v2 * v2;
        float w2 = ub * ub, z2 = vb * vb;
        ms[0] += ub * vb;  ms[1] += w2;       ms[2] += z2;
        ms[3] += w2 * vb;  ms[4] += ub * z2;
        ms[5] += w2 * ub;  ms[6] += z2 * vb;
        ms[7] += w2 * z2;  ms[8] += w2 * ub * vb; ms[9] += ub * z2 * vb;
        ms[10] += w2 * w2; ms[11] += z2 * z2;
    }
    float m[12];   // wave-uniform (SGPR) after DPP reduction
    #pragma unroll
    for (int k = 0; k < 12; ++k) m[k] = wave_sum(ms[k]);

    // ---- MLP: h1 = gelu(m @ W1 + b1); lane owns unit `lane`
    float a1 = b1[lane];
    #pragma unroll
    for (int k = 0; k < 12; ++k) a1 = fmaf(m[k], W1[k * 64 + lane], a1);
    float aval = gelu_f(a1) + s_emb[lane];

    // ---- h2 = gelu((h1+emb) @ W2a + b2a); lane owns units lane, lane+64.
    // Broadcast aval lane-by-lane through v_readlane (SGPR) — zero DS ops.
    float acc0 = b2a[lane];
    float acc1 = b2a[lane + 64];
    #pragma unroll
    for (int j = 0; j < 64; ++j) {
        float aj = __int_as_float(__builtin_amdgcn_readlane(__float_as_int(aval), j));
        acc0 = fmaf(aj, W2a[j * 128 + lane], acc0);
        acc1 = fmaf(aj, W2a[j * 128 + 64 + lane], acc1);
    }
    float h2lo = gelu_f(acc0), h2hi = gelu_f(acc1);

    // ---- h3 = gelu(h2 @ W2b + b2b): per-lane partials + DPP reduction
    float h3[12];  // wave-uniform
    #pragma unroll
    for (int k = 0; k < 12; ++k) {
        float p3 = fmaf(h2lo, W2b[lane * 12 + k], h2hi * W2b[(lane + 64) * 12 + k]);
        h3[k] = gelu_f(wave_sum(p3) + b2b[k]);
    }

    // ---- h = (h3 @ W2c + b2c) / sqrt(t)  (all-uniform scalar math)
    const float rst = rsqrtf(tval);
    float h[12];
    #pragma unroll
    for (int k = 0; k < 12; ++k) {
        float acc = b2c[k];
        #pragma unroll
        for (int j = 0; j < 12; ++j) acc = fmaf(h3[j], W2c[j * 12 + k], acc);
        h[k] = acc * rst;
    }

    // ---- per-sample correction constants (mean-shift term of the jacobian).
    // S0_k = sum u^(P-1) v^Q: degree-1 sums vanish (centered); others are moments.
    const float inv_n = 0.01f;
    float c0 = (2.0f*h[3]*m[0] + h[4]*m[2] + 3.0f*h[5]*m[1] + 2.0f*h[7]*m[4]
              + 3.0f*h[8]*m[3] + h[9]*m[6] + 4.0f*h[10]*m[5]) * inv_n;
    float c1 = (h[3]*m[1] + 2.0f*h[4]*m[0] + 3.0f*h[6]*m[2] + 2.0f*h[7]*m[3]
              + h[8]*m[5] + 3.0f*h[9]*m[4] + 4.0f*h[11]*m[6]) * inv_n;

    // cubic polynomial coefficients in (u, v) — all wave-uniform
    const float A1 = 2.0f*h[1], A2 = h[0],      A3 = 3.0f*h[5], A4 = 2.0f*h[3], A5 = h[4];
    const float A6 = 4.0f*h[10],A7 = 3.0f*h[8], A8 = 2.0f*h[7], A9 = h[9];
    const float B1 = h[0],      B2 = 2.0f*h[2], B3 = h[3],      B4 = 2.0f*h[4], B5 = 3.0f*h[6];
    const float B6 = h[8],      B7 = 2.0f*h[7], B8 = 3.0f*h[9], B9 = 4.0f*h[11];

    float2* pout = reinterpret_cast<float2*>(out) + (size_t)b * 100;
    {
        float u = ua, v = va;
        float u2 = u*u, v2 = v*v;
        float o0 = A1*u + A2*v + A3*u2 + A4*u*v + A5*v2 + A6*u2*u + A7*u2*v + A8*u*v2 + A9*v2*v - c0;
        float o1 = B1*u + B2*v + B3*u2 + B4*u*v + B5*v2 + B6*u2*u + B7*u2*v + B8*u*v2 + B9*v2*v - c1;
        float2 r; r.x = o0; r.y = o1;
        pout[lane] = r;
    }
    if (has2) {
        float u = ub, v = vb;
        float u2 = u*u, v2 = v*v;
        float o0 = A1*u + A2*v + A3*u2 + A4*u*v + A5*v2 + A6*u2*u + A7*u2*v + A8*u*v2 + A9*v2*v - c0;
        float o1 = B1*u + B2*v + B3*u2 + B4*u*v + B5*v2 + B6*u2*u + B7*u2*v + B8*u*v2 + B9*v2*v - c1;
        float2 r; r.x = o0; r.y = o1;
        pout[lane + 64] = r;
    }
}

extern "C" void kernel_launch(void* const* d_in, const int* in_sizes, int n_in,
                              void* d_out, int out_size, void* d_ws, size_t ws_size,
                              hipStream_t stream) {
    const float* x    = (const float*)d_in[0];
    const float* t    = (const float*)d_in[1];
    // d_in[2] = K (exponent table) — baked into the kernel as compile-time constants.
    const float* Wf   = (const float*)d_in[3];
    const float* embW = (const float*)d_in[4];
    const float* embB = (const float*)d_in[5];
    const float* W1   = (const float*)d_in[6];
    const float* b1   = (const float*)d_in[7];
    const float* W2a  = (const float*)d_in[8];
    const float* b2a  = (const float*)d_in[9];
    const float* W2b  = (const float*)d_in[10];
    const float* b2b  = (const float*)d_in[11];
    const float* W2c  = (const float*)d_in[12];
    const float* b2c  = (const float*)d_in[13];

    const int B = in_sizes[0] / 200;            // [B,100,2]
    const int blocks = (B + 3) / 4;             // 4 samples (waves) per block

    scorenet_fused<<<blocks, 256, 0, stream>>>(
        x, t, Wf, embW, embB, W1, b1, W2a, b2a, W2b, b2b, W2c, b2c,
        (float*)d_out, B);
}